// Round 3
// baseline (4834.861 us; speedup 1.0000x reference)
//
#include <hip/hip_runtime.h>

#define B_ 1024
#define T_ 366
#define NS_ 365
#define CD_ 24
#define NTASK (B_ * NS_)

__device__ __forceinline__ float sigm(float x) {
    return __fdividef(1.f, 1.f + __expf(-x));
}

// ---------------- Phase 1: recurrence, 4 waves per chain, wide phases ----------------
// Phase A (all): 2 register rows each; wave3: +1 redis row (volatile L1);
//                wave1 lanes 0..48: aux row + in-wave part/cons/assim softmax -> cmid
// Phase B (tid<192): row softmax, 8 threads/row x 3 elems
// Phase C (tid<192): column sums, 8 threads/col x 3 elems
__global__ __launch_bounds__(256, 4) void mclstm_phase1(
    const float* __restrict__ X, const float* __restrict__ ORY,
    const float* __restrict__ Wr, const float* __restrict__ br,
    const float* __restrict__ Wp, const float* __restrict__ bp,
    const float* __restrict__ Wc, const float* __restrict__ bc,
    const float* __restrict__ Wa, const float* __restrict__ ba,
    float* __restrict__ Ccell)
{
    const int b = blockIdx.x;
    const int tid = threadIdx.x;

    __shared__ alignas(16) float zbuf[CD_ * 25];   // 24 rows, stride 25
    __shared__ alignas(16) float cbuf[CD_];
    __shared__ float cmid[CD_];

    // two register-resident redis rows: tid, tid+256 (cols 0..23 + rad@25)
    float w0[25], w1[25], b0, b1;
    {
        const float* wa = Wr + (size_t)tid * 29;
        const float* wb = Wr + (size_t)(tid + 256) * 29;
#pragma unroll
        for (int k = 0; k < 24; ++k) { w0[k] = wa[k]; w1[k] = wb[k]; }
        w0[24] = wa[25]; w1[24] = wb[25];
        b0 = br[tid]; b1 = br[tid + 256];
    }
    // pin: origin becomes opaque -> no remat-from-memory, must stay in VGPRs
#pragma unroll
    for (int k = 0; k < 25; ++k) asm volatile("" : "+v"(w0[k]), "+v"(w1[k]));
    asm volatile("" : "+v"(b0), "+v"(b1));

    const int za0 = (tid / 24) * 25 + tid % 24;
    const int za1 = ((tid + 256) / 24) * 25 + (tid + 256) % 24;

    // third row: wave3 -> redis rows 512..575; threads 64..112 -> aux rows (L1, volatile)
    const volatile float* w2p = nullptr;
    float b2 = 0.f; int za2 = 0;
    int role = 0;                       // 1 = redis третья (wave3), 2 = aux (wave1)
    if (tid >= 192) {
        const int e = tid + 320;        // 512..575
        w2p = (const volatile float*)(Wr + (size_t)e * 29);
        b2 = br[e];
        za2 = (e / 24) * 25 + (e % 24);
        role = 1;
    } else if (tid >= 64 && tid < 113) {
        const int l2 = tid - 64;
        if (l2 < 24)      { w2p = (const volatile float*)(Wp + (size_t)l2 * 29);        b2 = bp[l2]; }
        else if (l2 < 48) { w2p = (const volatile float*)(Wc + (size_t)(l2 - 24) * 29); b2 = bc[l2 - 24]; }
        else              { w2p = (const volatile float*)Wa;                            b2 = ba[0]; }
        role = 2;
    }

    if (tid < CD_) cbuf[tid] = 0.f;
    __syncthreads();

    float Ncum = 0.f;
    const float* xrow = X + (size_t)b * T_ * 4;
    const float* orow = ORY + (size_t)b * T_ * 7;

    for (int t = 0; t < NS_; ++t) {
        const float rad = xrow[t * 4 + 0];
        const float tmx = xrow[t * 4 + 1];
        const float tmn = xrow[t * 4 + 2];
        Ncum += xrow[t * 4 + 3];
        const float dvs = orow[t * 7];

        const float tave = 0.5f * (tmx + tmn);
        const float cl = fminf(fmaxf(tave * 50.f, 10.f), 40.f);
        const float eff = 0.54f - (cl - 10.f) * (0.18f / 30.f);
        const float cpot = rad * (eff * (2.f * 0.5f / 3.6f * (12.f / 44.f)));

        float Cg[24];
#pragma unroll
        for (int q = 0; q < 6; ++q) {
            const float4 v = ((const float4*)cbuf)[q];
            Cg[4 * q + 0] = v.x; Cg[4 * q + 1] = v.y;
            Cg[4 * q + 2] = v.z; Cg[4 * q + 3] = v.w;
        }

        // --- Phase A: dot products (4-way split accumulators, short dep chains) ---
        {
            float p0 = b0, p1 = 0.f, p2 = 0.f, p3 = 0.f;
            float q0 = b1, q1 = 0.f, q2 = 0.f, q3 = 0.f;
#pragma unroll
            for (int k = 0; k < 24; k += 4) {
                p0 = fmaf(w0[k],     Cg[k],     p0);
                p1 = fmaf(w0[k + 1], Cg[k + 1], p1);
                p2 = fmaf(w0[k + 2], Cg[k + 2], p2);
                p3 = fmaf(w0[k + 3], Cg[k + 3], p3);
                q0 = fmaf(w1[k],     Cg[k],     q0);
                q1 = fmaf(w1[k + 1], Cg[k + 1], q1);
                q2 = fmaf(w1[k + 2], Cg[k + 2], q2);
                q3 = fmaf(w1[k + 3], Cg[k + 3], q3);
            }
            zbuf[za0] = fmaf(w0[24], rad, (p0 + p1) + (p2 + p3));
            zbuf[za1] = fmaf(w1[24], rad, (q0 + q1) + (q2 + q3));
        }

        if (role == 1) {                       // wave3: redis row 512..575
            float p0 = b2, p1 = 0.f, p2 = 0.f, p3 = 0.f;
#pragma unroll
            for (int k = 0; k < 24; k += 4) {
                p0 = fmaf(w2p[k],     Cg[k],     p0);
                p1 = fmaf(w2p[k + 1], Cg[k + 1], p1);
                p2 = fmaf(w2p[k + 2], Cg[k + 2], p2);
                p3 = fmaf(w2p[k + 3], Cg[k + 3], p3);
            }
            zbuf[za2] = fmaf(w2p[25], rad, (p0 + p1) + (p2 + p3));
        } else if (role == 2) {                // wave1 lanes 0..48: aux + softmax + cmid
            const int l2 = tid - 64;
            float pz = b2;
#pragma unroll
            for (int k = 0; k < 24; ++k) pz = fmaf(w2p[k], Cg[k], pz);
            pz = fmaf(w2p[24], dvs, pz);
            pz = fmaf(w2p[25], rad, pz);
            pz = fmaf(w2p[26], tmx, pz);
            pz = fmaf(w2p[27], tmn, pz);
            pz = fmaf(w2p[28], Ncum, pz);

            float pm = (l2 < 24) ? pz : -1e30f;
#pragma unroll
            for (int o = 1; o < 32; o <<= 1) pm = fmaxf(pm, __shfl_xor(pm, o, 32));
            float pe = (l2 < 24) ? __expf(pz - pm) : 0.f;
            float ps = pe;
#pragma unroll
            for (int o = 1; o < 32; o <<= 1) ps += __shfl_xor(ps, o, 32);
            const float conz = __shfl(pz, 24 + (l2 & 31), 64);  // cons z from lanes 24..47
            const float asmz = __shfl(pz, 48, 64);              // assim z from lane 48
            if (l2 < 24) {
                const float part = __fdividef(pe, ps);
                cmid[l2] = (cbuf[l2] + sigm(asmz) * cpot * part) * (1.f - sigm(conz));
            }
        }
        __syncthreads();                       // B1: zbuf + cmid ready

        // --- Phase B: row softmax, 8 threads per row ---
        if (tid < 192) {
            const int r = tid >> 3, i = tid & 7;
            const float z0v = zbuf[r * 25 + i];
            const float z1v = zbuf[r * 25 + i + 8];
            const float z2v = zbuf[r * 25 + i + 16];
            float m = fmaxf(fmaxf(z0v, z1v), z2v);
#pragma unroll
            for (int o = 1; o < 8; o <<= 1) m = fmaxf(m, __shfl_xor(m, o));
            const float e0 = __expf(z0v - m);
            const float e1 = __expf(z1v - m);
            const float e2 = __expf(z2v - m);
            float s = e0 + e1 + e2;
#pragma unroll
            for (int o = 1; o < 8; o <<= 1) s += __shfl_xor(s, o);
            const float fac = __fdividef(cmid[r], s);
            zbuf[r * 25 + i]      = e0 * fac;
            zbuf[r * 25 + i + 8]  = e1 * fac;
            zbuf[r * 25 + i + 16] = e2 * fac;
        }
        __syncthreads();                       // B2: scaled P ready

        // --- Phase C: column sums, 8 threads per column ---
        if (tid < 192) {
            const int c = tid >> 3, i = tid & 7;
            float s = zbuf[i * 25 + c] + zbuf[(i + 8) * 25 + c] + zbuf[(i + 16) * 25 + c];
#pragma unroll
            for (int o = 1; o < 8; o <<= 1) s += __shfl_xor(s, o);
            if (i == 0) {
                cbuf[c] = s;
                Ccell[((size_t)b * NS_ + t) * CD_ + c] = s;
            }
        }
        __syncthreads();                       // B3: C(t+1) visible
    }
}

// ---------------- Phase 2: C_conv + all_day, one (b,t) task per lane ----------------
__global__ __launch_bounds__(256, 4) void mclstm_phase2(
    const float* __restrict__ X, const float* __restrict__ ORY,
    const float* __restrict__ Wr, const float* __restrict__ br,
    const float* __restrict__ c2a, const float* __restrict__ g2y,
    const float* __restrict__ Ccell, float* __restrict__ allday,
    float* __restrict__ Cconv)
{
    const int tid = blockIdx.x * 256 + threadIdx.x;

    if (tid < B_) {
#pragma unroll
        for (int k = 0; k < 7; ++k)
            allday[(size_t)tid * T_ * 7 + k] = ORY[(size_t)tid * T_ * 7 + k];
    }
    if (tid >= NTASK) return;
    const int b = tid / NS_;
    const int t = tid - b * NS_;

    const float* Cp = Ccell + (size_t)tid * CD_;
    float C[24];
#pragma unroll
    for (int q = 0; q < 6; ++q) {
        const float4 v = *(const float4*)(Cp + 4 * q);
        C[4 * q + 0] = v.x; C[4 * q + 1] = v.y; C[4 * q + 2] = v.z; C[4 * q + 3] = v.w;
    }
    const float rad = X[((size_t)b * T_ + t) * 4];

    float Cc[24];
#pragma unroll
    for (int c = 0; c < 24; ++c) Cc[c] = 0.f;

    for (int r = 0; r < 24; ++r) {
        float z[24];
#pragma unroll
        for (int c = 0; c < 24; ++c) {
            const float* w = Wr + (r * 24 + c) * 29;
            float zz = fmaf(w[25], rad, br[r * 24 + c]);
#pragma unroll
            for (int k = 0; k < 24; ++k) zz = fmaf(w[k], C[k], zz);
            z[c] = zz;
        }
        float m = z[0];
#pragma unroll
        for (int c = 1; c < 24; ++c) m = fmaxf(m, z[c]);
        float ss = 0.f;
#pragma unroll
        for (int c = 0; c < 24; ++c) { z[c] = __expf(z[c] - m); ss += z[c]; }
        const float fac = __fdividef(Cp[r], ss);
#pragma unroll
        for (int c = 0; c < 24; ++c) Cc[c] = fmaf(z[c], fac, Cc[c]);
    }

    float* cv = Cconv + (size_t)tid * CD_;
#pragma unroll
    for (int q = 0; q < 6; ++q) {
        float4 v;
        v.x = Cc[4 * q + 0]; v.y = Cc[4 * q + 1]; v.z = Cc[4 * q + 2]; v.w = Cc[4 * q + 3];
        *(float4*)(cv + 4 * q) = v;
    }

    float pai = 0.f;
#pragma unroll
    for (int c = 0; c < 24; ++c) pai += fabsf(C[c] * c2a[c]);
    float lea = 0.f, ste = 0.f, gra = 0.f, yie = 0.f;
#pragma unroll
    for (int c = 0; c < 8; ++c) lea += C[c];
#pragma unroll
    for (int c = 8; c < 16; ++c) ste += C[c];
#pragma unroll
    for (int c = 16; c < 24; ++c) { gra += C[c]; yie += fabsf(C[c] * g2y[c - 16]); }
    lea /= 0.419f; ste /= 0.431f; gra /= 0.487f; yie /= 0.487f;
    const float agb = lea + ste + gra;

    float* ad = allday + ((size_t)b * T_ + (t + 1)) * 7;
    ad[0] = ORY[((size_t)b * T_ + (t + 1)) * 7];
    ad[1] = pai; ad[2] = lea; ad[3] = ste; ad[4] = gra; ad[5] = agb; ad[6] = yie;
}

extern "C" void kernel_launch(void* const* d_in, const int* in_sizes, int n_in,
                              void* d_out, int out_size, void* d_ws, size_t ws_size,
                              hipStream_t stream) {
    const float* X   = (const float*)d_in[0];
    const float* ORY = (const float*)d_in[1];
    const float* Wr  = (const float*)d_in[2];
    const float* br  = (const float*)d_in[3];
    const float* Wp  = (const float*)d_in[4];
    const float* bp  = (const float*)d_in[5];
    const float* Wc  = (const float*)d_in[6];
    const float* bc  = (const float*)d_in[7];
    const float* Wa  = (const float*)d_in[8];
    const float* ba  = (const float*)d_in[9];
    const float* c2a = (const float*)d_in[10];
    const float* g2y = (const float*)d_in[11];

    float* allday = (float*)d_out;
    float* Ccell  = allday + (size_t)B_ * T_ * 7;
    float* Cconv  = Ccell + (size_t)B_ * NS_ * CD_;

    hipLaunchKernelGGL(mclstm_phase1, dim3(B_), dim3(256), 0, stream,
                       X, ORY, Wr, br, Wp, bp, Wc, bc, Wa, ba, Ccell);
    hipLaunchKernelGGL(mclstm_phase2, dim3(NTASK / 256), dim3(256), 0, stream,
                       X, ORY, Wr, br, c2a, g2y, Ccell, allday, Cconv);
}

// Round 4
// 894.265 us; speedup vs baseline: 5.4065x; 5.4065x over previous
//
#include <hip/hip_runtime.h>

#define B_ 1024
#define T_ 366
#define NS_ 365
#define CD_ 24
#define NTASK (B_ * NS_)

__device__ __forceinline__ float sigm(float x) {
    return __fdividef(1.f, 1.f + __expf(-x));
}

// ---------------- Phase 1: recurrence + folded C_conv, 2 chains per block ----------------
// LDS-resident weights (stride 27, conflict-free). 512 blocks, 2 blocks/CU.
// Iter u (0..365): D[e] = bias + W[e,:24]·C_u  (shared dot)
//   z1[e] = D + w_rad[e]*rad_u      -> redis1 of step u       (u < 365)
//   z2[e] = D + w_rad[e]*rad_{u-1}  -> redis2 of step u-1     (u > 0)
__global__ __launch_bounds__(256, 2) void mclstm_phase1(
    const float* __restrict__ X, const float* __restrict__ ORY,
    const float* __restrict__ Wr, const float* __restrict__ br,
    const float* __restrict__ Wp, const float* __restrict__ bp,
    const float* __restrict__ Wc, const float* __restrict__ bc,
    const float* __restrict__ Wa, const float* __restrict__ ba,
    float* __restrict__ Ccell, float* __restrict__ Cconv)
{
    __shared__ float Wl[576 * 27];   // [e*27]: w[0..23], [24]=W[e][25] (rad), [25]=bias
    __shared__ float Al[49 * 31];    // aux rows: w[0..28], [29]=bias
    __shared__ float zb[2][2][600];  // [chain][kind 0=redis1 1=conv][r*25+c]
    __shared__ float cbuf[2][24];
    __shared__ float cmid[2][24];

    const int tid = threadIdx.x;
    const int b0 = blockIdx.x * 2;

    // ---- stage weights into LDS ----
    for (int i = tid; i < 576 * 26; i += 256) {
        const int row = i / 26, col = i - row * 26;
        float v;
        if (col < 24)      v = Wr[row * 29 + col];
        else if (col == 24) v = Wr[row * 29 + 25];
        else                v = br[row];
        Wl[row * 27 + col] = v;
    }
    for (int i = tid; i < 49 * 30; i += 256) {
        const int row = i / 30, col = i - row * 30;
        float v;
        if (col < 29) v = (row < 24) ? Wp[row * 29 + col]
                        : (row < 48) ? Wc[(row - 24) * 29 + col] : Wa[col];
        else          v = (row < 24) ? bp[row] : (row < 48) ? bc[row - 24] : ba[0];
        Al[row * 31 + col] = v;
    }
    if (tid < 48) ((float*)cbuf)[tid] = 0.f;

    const int e0 = tid, e1 = tid + 256, e2 = tid + 320;
    const bool has3 = (tid >= 192);
    const int za0 = (e0 / 24) * 25 + e0 % 24;
    const int za1 = (e1 / 24) * 25 + e1 % 24;
    const int za2 = (e2 / 24) * 25 + e2 % 24;

    const int wv = tid >> 6, la = tid & 63;
    const bool auxAct = (wv == 1 || wv == 2) && la < 49;
    const int ja = wv - 1;   // aux chain

    const float* x0 = X + (size_t)b0 * T_ * 4;
    const float* x1 = X + (size_t)(b0 + 1) * T_ * 4;
    const float* xa = (ja == 1) ? x1 : x0;
    const float* oa = ORY + (size_t)(b0 + (ja == 1 ? 1 : 0)) * T_ * 7;

    // phase B/C task decode (tid < 192)
    const int jj = tid / 96;
    const int rem = tid - jj * 96;
    const int kind = rem / 48;
    const int rr = rem - kind * 48;
    const int rowc = rr >> 1, half = rr & 1;

    __syncthreads();

    float radp0 = 0.f, radp1 = 0.f, Ncum = 0.f;

    for (int u = 0; u <= NS_; ++u) {
        const bool do1 = (u < NS_), doCv = (u > 0);
        const float radu0 = x0[u * 4], radu1 = x1[u * 4];

        float Cg0[24], Cg1[24];
#pragma unroll
        for (int q = 0; q < 6; ++q) {
            const float4 a = ((const float4*)cbuf[0])[q];
            const float4 b = ((const float4*)cbuf[1])[q];
            Cg0[4 * q] = a.x; Cg0[4 * q + 1] = a.y; Cg0[4 * q + 2] = a.z; Cg0[4 * q + 3] = a.w;
            Cg1[4 * q] = b.x; Cg1[4 * q + 1] = b.y; Cg1[4 * q + 2] = b.z; Cg1[4 * q + 3] = b.w;
        }

        // ---- aux row + part/cons/assim + cmid (waves 1,2) ----
        if (auxAct && do1) {
            const float radj = (ja == 1) ? radu1 : radu0;
            const float tmx = xa[u * 4 + 1], tmn = xa[u * 4 + 2];
            Ncum += xa[u * 4 + 3];
            const float dvs = oa[u * 7];
            const float tave = 0.5f * (tmx + tmn);
            const float cl = fminf(fmaxf(tave * 50.f, 10.f), 40.f);
            const float eff = 0.54f - (cl - 10.f) * (0.18f / 30.f);
            const float cpot = radj * (eff * (2.f * 0.5f / 3.6f * (12.f / 44.f)));

            const float* ap = Al + la * 31;
            float z = ap[29];
            if (ja == 0) {
#pragma unroll
                for (int k = 0; k < 24; ++k) z = fmaf(ap[k], Cg0[k], z);
            } else {
#pragma unroll
                for (int k = 0; k < 24; ++k) z = fmaf(ap[k], Cg1[k], z);
            }
            z = fmaf(ap[24], dvs, z);
            z = fmaf(ap[25], radj, z);
            z = fmaf(ap[26], tmx, z);
            z = fmaf(ap[27], tmn, z);
            z = fmaf(ap[28], Ncum, z);

            float pm = (la < 24) ? z : -1e30f;
#pragma unroll
            for (int o = 1; o < 32; o <<= 1) pm = fmaxf(pm, __shfl_xor(pm, o, 32));
            float pe = (la < 24) ? __expf(z - pm) : 0.f;
            float ps = pe;
#pragma unroll
            for (int o = 1; o < 32; o <<= 1) ps += __shfl_xor(ps, o, 32);
            const float conz = __shfl(z, 24 + (la & 31), 64);
            const float asmz = __shfl(z, 48, 64);
            if (la < 24) {
                const float part = __fdividef(pe, ps);
                cmid[ja][la] = (cbuf[ja][la] + sigm(asmz) * cpot * part) * (1.f - sigm(conz));
            }
        }

        // ---- main redis rows: shared dot, two z's ----
#define DO_ROW(E, ZA)                                                          \
        {                                                                      \
            const float* wp = Wl + (E) * 27;                                   \
            float w[24];                                                       \
            _Pragma("unroll") for (int k = 0; k < 24; ++k) w[k] = wp[k];       \
            const float w24 = wp[24], bias = wp[25];                           \
            float D0 = bias, D1 = bias;                                        \
            _Pragma("unroll") for (int k = 0; k < 24; ++k) {                   \
                D0 = fmaf(w[k], Cg0[k], D0);                                   \
                D1 = fmaf(w[k], Cg1[k], D1);                                   \
            }                                                                  \
            if (do1)  { zb[0][0][ZA] = fmaf(w24, radu0, D0);                   \
                        zb[1][0][ZA] = fmaf(w24, radu1, D1); }                 \
            if (doCv) { zb[0][1][ZA] = fmaf(w24, radp0, D0);                   \
                        zb[1][1][ZA] = fmaf(w24, radp1, D1); }                 \
        }
        DO_ROW(e0, za0)
        DO_ROW(e1, za1)
        if (has3) DO_ROW(e2, za2)
#undef DO_ROW
        __syncthreads();   // B1: zb + cmid ready

        // ---- phase B: row softmax (2 threads/row, 12 elems) ----
        if (tid < 192 && ((kind == 0) ? do1 : doCv)) {
            float* zp = &zb[jj][kind][rowc * 25 + half * 12];
            float z[12];
#pragma unroll
            for (int i = 0; i < 12; ++i) z[i] = zp[i];
            float m = z[0];
#pragma unroll
            for (int i = 1; i < 12; ++i) m = fmaxf(m, z[i]);
            m = fmaxf(m, __shfl_xor(m, 1));
            float s = 0.f;
#pragma unroll
            for (int i = 0; i < 12; ++i) { z[i] = __expf(z[i] - m); s += z[i]; }
            s += __shfl_xor(s, 1);
            const float num = (kind == 0) ? cmid[jj][rowc] : cbuf[jj][rowc];
            const float fac = __fdividef(num, s);
#pragma unroll
            for (int i = 0; i < 12; ++i) zp[i] = z[i] * fac;
        }
        __syncthreads();   // B2: scaled P ready

        // ---- phase C: column sums ----
        if (tid < 192 && ((kind == 0) ? do1 : doCv)) {
            const int c = rowc;
            float s = 0.f;
#pragma unroll
            for (int i = 0; i < 12; ++i) s += zb[jj][kind][(half * 12 + i) * 25 + c];
            s += __shfl_xor(s, 1);
            if (half == 0) {
                if (kind == 0) {
                    cbuf[jj][c] = s;
                    Ccell[((size_t)(b0 + jj) * NS_ + u) * CD_ + c] = s;
                } else {
                    Cconv[((size_t)(b0 + jj) * NS_ + (u - 1)) * CD_ + c] = s;
                }
            }
        }
        __syncthreads();   // B3: C(t+1) visible
        radp0 = radu0; radp1 = radu1;
    }
}

// ---------------- Epilogue: all_day from Ccell (streaming) ----------------
__global__ __launch_bounds__(256) void mclstm_allday(
    const float* __restrict__ ORY, const float* __restrict__ c2a,
    const float* __restrict__ g2y, const float* __restrict__ Ccell,
    float* __restrict__ allday)
{
    const int tid = blockIdx.x * 256 + threadIdx.x;
    if (tid < B_) {
#pragma unroll
        for (int k = 0; k < 7; ++k)
            allday[(size_t)tid * T_ * 7 + k] = ORY[(size_t)tid * T_ * 7 + k];
    }
    if (tid >= NTASK) return;
    const int b = tid / NS_;
    const int t = tid - b * NS_;

    const float* Cp = Ccell + (size_t)tid * CD_;
    float C[24];
#pragma unroll
    for (int q = 0; q < 6; ++q) {
        const float4 v = *(const float4*)(Cp + 4 * q);
        C[4 * q] = v.x; C[4 * q + 1] = v.y; C[4 * q + 2] = v.z; C[4 * q + 3] = v.w;
    }
    float pai = 0.f;
#pragma unroll
    for (int c = 0; c < 24; ++c) pai += fabsf(C[c] * c2a[c]);
    float lea = 0.f, ste = 0.f, gra = 0.f, yie = 0.f;
#pragma unroll
    for (int c = 0; c < 8; ++c) lea += C[c];
#pragma unroll
    for (int c = 8; c < 16; ++c) ste += C[c];
#pragma unroll
    for (int c = 16; c < 24; ++c) { gra += C[c]; yie += fabsf(C[c] * g2y[c - 16]); }
    lea /= 0.419f; ste /= 0.431f; gra /= 0.487f; yie /= 0.487f;
    const float agb = lea + ste + gra;

    float* ad = allday + ((size_t)b * T_ + (t + 1)) * 7;
    ad[0] = ORY[((size_t)b * T_ + (t + 1)) * 7];
    ad[1] = pai; ad[2] = lea; ad[3] = ste; ad[4] = gra; ad[5] = agb; ad[6] = yie;
}

extern "C" void kernel_launch(void* const* d_in, const int* in_sizes, int n_in,
                              void* d_out, int out_size, void* d_ws, size_t ws_size,
                              hipStream_t stream) {
    const float* X   = (const float*)d_in[0];
    const float* ORY = (const float*)d_in[1];
    const float* Wr  = (const float*)d_in[2];
    const float* br  = (const float*)d_in[3];
    const float* Wp  = (const float*)d_in[4];
    const float* bp  = (const float*)d_in[5];
    const float* Wc  = (const float*)d_in[6];
    const float* bc  = (const float*)d_in[7];
    const float* Wa  = (const float*)d_in[8];
    const float* ba  = (const float*)d_in[9];
    const float* c2a = (const float*)d_in[10];
    const float* g2y = (const float*)d_in[11];

    float* allday = (float*)d_out;
    float* Ccell  = allday + (size_t)B_ * T_ * 7;
    float* Cconv  = Ccell + (size_t)B_ * NS_ * CD_;

    hipLaunchKernelGGL(mclstm_phase1, dim3(B_ / 2), dim3(256), 0, stream,
                       X, ORY, Wr, br, Wp, bp, Wc, bc, Wa, ba, Ccell, Cconv);
    hipLaunchKernelGGL(mclstm_allday, dim3((NTASK + 255) / 256), dim3(256), 0, stream,
                       ORY, c2a, g2y, Ccell, allday);
}